// Round 3
// baseline (302.899 us; speedup 1.0000x reference)
//
#include <hip/hip_runtime.h>

// DiffeomorphicTransform R13: R10-verbatim hot kernel + fused step-1.
//
// R12 post-mortem: identical mid-step source ran 43.4us vs R10's 40.8us; VGPR
// fell 28->24 because the added <SRC_PLANAR> template instantiations perturbed
// regalloc of the hot <false,false> kernel (co-compilation effect), serializing
// the 8 gather loads. R13 restores R10's exact template (float3 src, two
// instantiations) and isolates the step-1 planar-velocity fusion in a separate
// standalone kernel (replacing repack_scale in the module). Nontemporal final
// store dropped (unproven, suspect). Keeps: zero-repack structure (step 1 reads
// velocity directly, exact 2^-7 fold - bit-identical, validated R11/R12),
// z-slab XCD swizzle (R6), analytic identity grid (R3).
//
// Lane-request floor model: 10 vmem instrs/voxel (1 self + 8 gather + 1 store)
// x 64 lanes x 160 waves/CU / 2.4GHz = 42.7us/step at 1 addr/cyc/CU; R10's
// 40.8us/step shows better-than-1/cyc when enough loads are in flight. 8 gather
// instrs (4 rows x 24B span) is the fp32-trilinear floor for any layout (6
// floats/row > 16B => >=2 loads/row; R11 cube-float4 regressed).

constexpr int D = 128, H = 160, W = 128;
constexpr int N = D * H * W;             // 2,621,440 voxels
constexpr int VOX_BLOCKS = N / 256;      // 10240 blocks
constexpr int NUM_XCD = 8;
constexpr int CHUNKS_PER_XCD = VOX_BLOCKS / NUM_XCD;   // 1280

struct alignas(4) f2 { float a, b; };    // 4B-aligned pair load

// ---- step 1: planar velocity -> interleaved, repack fused (standalone) ----
__global__ __launch_bounds__(256)
void diffeo_first(const float* __restrict__ vel,   // [3][N] planar
                  const float* __restrict__ rf_p,
                  float3* __restrict__ dst3)       // [N][3]
{
    const int b   = blockIdx.x;
    const int xcd = b & (NUM_XCD - 1);
    const int k   = b >> 3;
    const int vb  = xcd * CHUNKS_PER_XCD + k;
    const int i   = vb * 256 + threadIdx.x;

    const float rf = rf_p[0];
    const float s  = 1.0f / 128.0f;          // 2^-7, exact

    const int x = i & (W - 1);
    const int r = i >> 7;
    const int y = r % H;
    const int z = r / H;

    const float3 f = make_float3(vel[i] * s, vel[i + N] * s, vel[i + 2 * N] * s);

    const float ix = fminf(fmaxf((float)x + f.x * (rf * 0.5f * (float)(W - 1)), 0.0f), (float)(W - 1));
    const float iy = fminf(fmaxf((float)y + f.y * (rf * 0.5f * (float)(H - 1)), 0.0f), (float)(H - 1));
    const float iz = fminf(fmaxf((float)z + f.z * (rf * 0.5f * (float)(D - 1)), 0.0f), (float)(D - 1));

    const float x0f = floorf(ix), y0f = floorf(iy), z0f = floorf(iz);
    const float wx = ix - x0f, wy = iy - y0f, wz = iz - z0f;
    const int x0 = (int)x0f, y0 = (int)y0f, z0 = (int)z0f;
    const int y1 = min(y0 + 1, H - 1);
    const int z1 = min(z0 + 1, D - 1);

    const int xb = min(x0, W - 2);
    const bool hix = (x0 == W - 1);

    int ofs[4];
    ofs[0] = (z0 * H + y0) * W + xb;
    ofs[1] = (z0 * H + y1) * W + xb;
    ofs[2] = (z1 * H + y0) * W + xb;
    ofs[3] = (z1 * H + y1) * W + xb;

    float3 p0[4], p1[4];
#pragma unroll
    for (int q = 0; q < 4; ++q) {
        const f2 px = *(const f2*)(vel + ofs[q]);
        const f2 py = *(const f2*)(vel + N + ofs[q]);
        const f2 pz = *(const f2*)(vel + 2 * N + ofs[q]);
        p0[q] = make_float3(px.a * s, py.a * s, pz.a * s);
        p1[q] = make_float3(px.b * s, py.b * s, pz.b * s);
    }
    if (hix) {
#pragma unroll
        for (int q = 0; q < 4; ++q) p0[q] = p1[q];   // wx==0 here, exact
    }

    const float omx = 1.0f - wx, omy = 1.0f - wy, omz = 1.0f - wz;
    const float w00 = omz * omy, w01 = omz * wy, w10 = wz * omy, w11 = wz * wy;

    const float vx = w00 * (omx * p0[0].x + wx * p1[0].x)
                   + w01 * (omx * p0[1].x + wx * p1[1].x)
                   + w10 * (omx * p0[2].x + wx * p1[2].x)
                   + w11 * (omx * p0[3].x + wx * p1[3].x);
    const float vy = w00 * (omx * p0[0].y + wx * p1[0].y)
                   + w01 * (omx * p0[1].y + wx * p1[1].y)
                   + w10 * (omx * p0[2].y + wx * p1[2].y)
                   + w11 * (omx * p0[3].y + wx * p1[3].y);
    const float vz = w00 * (omx * p0[0].z + wx * p1[0].z)
                   + w01 * (omx * p0[1].z + wx * p1[1].z)
                   + w10 * (omx * p0[2].z + wx * p1[2].z)
                   + w11 * (omx * p0[3].z + wx * p1[3].z);

    dst3[i] = make_float3(f.x + vx, f.y + vy, f.z + vz);
}

// ---- steps 2..7: VERBATIM R10 hot kernel ----
template <bool PLANAR_OUT>
__global__ __launch_bounds__(256)
void diffeo_step(const float3* __restrict__ src3,  // [N][3] flow
                 const float* __restrict__ rf_p,   // scalar range_flow
                 void* __restrict__ dst_raw)       // [N][3] or planar [3][N]
{
    // z-slab XCD swizzle (R6-validated)
    const int b   = blockIdx.x;              // 0..10239
    const int xcd = b & (NUM_XCD - 1);
    const int k   = b >> 3;                  // 0..1279
    const int vb  = xcd * CHUNKS_PER_XCD + k;
    const int i   = vb * 256 + threadIdx.x;  // voxel id [0,N)

    const float rf = rf_p[0];

    // voxel coords (W=128 pow2)
    const int x = i & (W - 1);
    const int r = i >> 7;                    // z*H + y
    const int y = r % H;
    const int z = r / H;

    const float3 f = src3[i];                // this voxel's flow (all channels)

    // analytic identity grid: unnormalized coord = x + flow*rf*0.5*(dim-1)
    const float ix = fminf(fmaxf((float)x + f.x * (rf * 0.5f * (float)(W - 1)), 0.0f), (float)(W - 1));
    const float iy = fminf(fmaxf((float)y + f.y * (rf * 0.5f * (float)(H - 1)), 0.0f), (float)(H - 1));
    const float iz = fminf(fmaxf((float)z + f.z * (rf * 0.5f * (float)(D - 1)), 0.0f), (float)(D - 1));

    const float x0f = floorf(ix), y0f = floorf(iy), z0f = floorf(iz);
    const float wx = ix - x0f, wy = iy - y0f, wz = iz - z0f;
    const int x0 = (int)x0f, y0 = (int)y0f, z0 = (int)z0f;
    const int y1 = min(y0 + 1, H - 1);
    const int z1 = min(z0 + 1, D - 1);

    // corner-pair base: x0==W-1 implies wx==0 (x1==x0) -> select hi triplet.
    const int xb = min(x0, W - 2);
    const bool hix = (x0 == W - 1);

    int ofs[4];
    ofs[0] = (z0 * H + y0) * W + xb;
    ofs[1] = (z0 * H + y1) * W + xb;
    ofs[2] = (z1 * H + y0) * W + xb;
    ofs[3] = (z1 * H + y1) * W + xb;

    // 8 gathers: per row-corner, two adjacent float3 triplets (24 contiguous
    // bytes covering x0 and x1 for ALL 3 channels -> ~1 line per row-corner)
    float3 p0[4], p1[4];
#pragma unroll
    for (int q = 0; q < 4; ++q) {
        p0[q] = src3[ofs[q]];
        p1[q] = src3[ofs[q] + 1];
    }
    if (hix) {
#pragma unroll
        for (int q = 0; q < 4; ++q) p0[q] = p1[q];   // wx==0 here, exact
    }

    const float omx = 1.0f - wx, omy = 1.0f - wy, omz = 1.0f - wz;
    const float w00 = omz * omy, w01 = omz * wy, w10 = wz * omy, w11 = wz * wy;

    // bilinear over (z,y) of the x-lerped corner values, per channel
    const float vx = w00 * (omx * p0[0].x + wx * p1[0].x)
                   + w01 * (omx * p0[1].x + wx * p1[1].x)
                   + w10 * (omx * p0[2].x + wx * p1[2].x)
                   + w11 * (omx * p0[3].x + wx * p1[3].x);
    const float vy = w00 * (omx * p0[0].y + wx * p1[0].y)
                   + w01 * (omx * p0[1].y + wx * p1[1].y)
                   + w10 * (omx * p0[2].y + wx * p1[2].y)
                   + w11 * (omx * p0[3].y + wx * p1[3].y);
    const float vz = w00 * (omx * p0[0].z + wx * p1[0].z)
                   + w01 * (omx * p0[1].z + wx * p1[1].z)
                   + w10 * (omx * p0[2].z + wx * p1[2].z)
                   + w11 * (omx * p0[3].z + wx * p1[3].z);

    const float o0 = f.x + vx, o1 = f.y + vy, o2 = f.z + vz;

    if (PLANAR_OUT) {
        float* __restrict__ dp = (float*)dst_raw;
        dp[i] = o0; dp[i + N] = o1; dp[i + 2 * N] = o2;
    } else {
        ((float3*)dst_raw)[i] = make_float3(o0, o1, o2);
    }
}

extern "C" void kernel_launch(void* const* d_in, const int* in_sizes, int n_in,
                              void* d_out, int out_size, void* d_ws, size_t ws_size,
                              hipStream_t stream)
{
    const float* vel = (const float*)d_in[0];   // [1,3,128,160,128] planar
    const float* rf  = (const float*)d_in[2];   // scalar range_flow
    float3* out3 = (float3*)d_out;              // d_out reused as interleaved scratch
    float3* ws3  = (float3*)d_ws;               // interleaved buffer

    const dim3 blk(256);
    const dim3 grd(VOX_BLOCKS);                 // 10240 blocks

    // 7 dispatches, R10 ping-pong pattern (ws <-> out3), no repack
    diffeo_first<<<grd, blk, 0, stream>>>(vel, rf, out3);              // s1: vel -> out3
    diffeo_step<false><<<grd, blk, 0, stream>>>(out3, rf, ws3);        // s2
    diffeo_step<false><<<grd, blk, 0, stream>>>(ws3,  rf, out3);       // s3
    diffeo_step<false><<<grd, blk, 0, stream>>>(out3, rf, ws3);        // s4
    diffeo_step<false><<<grd, blk, 0, stream>>>(ws3,  rf, out3);       // s5
    diffeo_step<false><<<grd, blk, 0, stream>>>(out3, rf, ws3);        // s6
    // step 7: interleaved ws -> PLANAR d_out (full overwrite, no aliasing)
    diffeo_step<true ><<<grd, blk, 0, stream>>>(ws3,  rf, d_out);      // s7
}

// Round 4
// 297.836 us; speedup vs baseline: 1.0170x; 1.0170x over previous
//
#include <hip/hip_runtime.h>

// DiffeomorphicTransform R14: CONTROL — byte-exact resubmission of R10 (the
// 296.5us best-on-record) to discriminate environment drift vs structure.
// R12/R13 ran the source-identical step kernel at 43us vs R10's <=40us; this
// run decides whether 296.5 is reproducible today. Pre-committed: reproduce ->
// investigate the repack-module effect; ~310 -> drift confirmed, R13 stands as
// best and the divergent-gather request floor (~43us/step) is the roofline.

constexpr int D = 128, H = 160, W = 128;
constexpr int N = D * H * W;             // 2,621,440 voxels
constexpr int VOX_BLOCKS = N / 256;      // 10240 blocks
constexpr int NUM_XCD = 8;
constexpr int CHUNKS_PER_XCD = VOX_BLOCKS / NUM_XCD;   // 1280

__global__ __launch_bounds__(256)
void repack_scale(const float* __restrict__ vel,   // [3][N] planar
                  float3* __restrict__ dst3)       // [N][3] interleaved
{
    const int i = blockIdx.x * blockDim.x + threadIdx.x;
    const float s = 1.0f / 128.0f;                 // 2^-7, exact
    dst3[i] = make_float3(vel[i] * s, vel[i + N] * s, vel[i + 2 * N] * s);
}

template <bool PLANAR_OUT>
__global__ __launch_bounds__(256)
void diffeo_step(const float3* __restrict__ src3,  // [N][3] flow
                 const float* __restrict__ rf_p,   // scalar range_flow
                 void* __restrict__ dst_raw)       // [N][3] or planar [3][N]
{
    // z-slab XCD swizzle (R6-validated)
    const int b   = blockIdx.x;              // 0..10239
    const int xcd = b & (NUM_XCD - 1);
    const int k   = b >> 3;                  // 0..1279
    const int vb  = xcd * CHUNKS_PER_XCD + k;
    const int i   = vb * 256 + threadIdx.x;  // voxel id [0,N)

    const float rf = rf_p[0];

    // voxel coords (W=128 pow2)
    const int x = i & (W - 1);
    const int r = i >> 7;                    // z*H + y
    const int y = r % H;
    const int z = r / H;

    const float3 f = src3[i];                // this voxel's flow (all channels)

    // analytic identity grid: unnormalized coord = x + flow*rf*0.5*(dim-1)
    const float ix = fminf(fmaxf((float)x + f.x * (rf * 0.5f * (float)(W - 1)), 0.0f), (float)(W - 1));
    const float iy = fminf(fmaxf((float)y + f.y * (rf * 0.5f * (float)(H - 1)), 0.0f), (float)(H - 1));
    const float iz = fminf(fmaxf((float)z + f.z * (rf * 0.5f * (float)(D - 1)), 0.0f), (float)(D - 1));

    const float x0f = floorf(ix), y0f = floorf(iy), z0f = floorf(iz);
    const float wx = ix - x0f, wy = iy - y0f, wz = iz - z0f;
    const int x0 = (int)x0f, y0 = (int)y0f, z0 = (int)z0f;
    const int y1 = min(y0 + 1, H - 1);
    const int z1 = min(z0 + 1, D - 1);

    // corner-pair base: x0==W-1 implies wx==0 (x1==x0) -> select hi triplet.
    const int xb = min(x0, W - 2);
    const bool hix = (x0 == W - 1);

    int ofs[4];
    ofs[0] = (z0 * H + y0) * W + xb;
    ofs[1] = (z0 * H + y1) * W + xb;
    ofs[2] = (z1 * H + y0) * W + xb;
    ofs[3] = (z1 * H + y1) * W + xb;

    // 8 gathers: per row-corner, two adjacent float3 triplets (24 contiguous
    // bytes covering x0 and x1 for ALL 3 channels -> ~1 line per row-corner)
    float3 p0[4], p1[4];
#pragma unroll
    for (int q = 0; q < 4; ++q) {
        p0[q] = src3[ofs[q]];
        p1[q] = src3[ofs[q] + 1];
    }
    if (hix) {
#pragma unroll
        for (int q = 0; q < 4; ++q) p0[q] = p1[q];   // wx==0 here, exact
    }

    const float omx = 1.0f - wx, omy = 1.0f - wy, omz = 1.0f - wz;
    const float w00 = omz * omy, w01 = omz * wy, w10 = wz * omy, w11 = wz * wy;

    // bilinear over (z,y) of the x-lerped corner values, per channel
    const float vx = w00 * (omx * p0[0].x + wx * p1[0].x)
                   + w01 * (omx * p0[1].x + wx * p1[1].x)
                   + w10 * (omx * p0[2].x + wx * p1[2].x)
                   + w11 * (omx * p0[3].x + wx * p1[3].x);
    const float vy = w00 * (omx * p0[0].y + wx * p1[0].y)
                   + w01 * (omx * p0[1].y + wx * p1[1].y)
                   + w10 * (omx * p0[2].y + wx * p1[2].y)
                   + w11 * (omx * p0[3].y + wx * p1[3].y);
    const float vz = w00 * (omx * p0[0].z + wx * p1[0].z)
                   + w01 * (omx * p0[1].z + wx * p1[1].z)
                   + w10 * (omx * p0[2].z + wx * p1[2].z)
                   + w11 * (omx * p0[3].z + wx * p1[3].z);

    const float o0 = f.x + vx, o1 = f.y + vy, o2 = f.z + vz;

    if (PLANAR_OUT) {
        float* __restrict__ dp = (float*)dst_raw;
        dp[i] = o0; dp[i + N] = o1; dp[i + 2 * N] = o2;
    } else {
        ((float3*)dst_raw)[i] = make_float3(o0, o1, o2);
    }
}

extern "C" void kernel_launch(void* const* d_in, const int* in_sizes, int n_in,
                              void* d_out, int out_size, void* d_ws, size_t ws_size,
                              hipStream_t stream)
{
    const float* vel = (const float*)d_in[0];   // [1,3,128,160,128] planar
    const float* rf  = (const float*)d_in[2];   // scalar range_flow
    float3* out3 = (float3*)d_out;              // d_out reused as interleaved scratch
    float3* ws3  = (float3*)d_ws;               // 31.5 MB interleaved buffer

    const dim3 blk(256);
    const dim3 grd(VOX_BLOCKS);                 // 10240 blocks

    // prologue: planar velocity -> interleaved ws, exact /2^7 folded in
    repack_scale<<<grd, blk, 0, stream>>>(vel, ws3);

    // steps 1..6 ping-pong interleaved: ws->out3->ws->out3->ws->out3->ws
    diffeo_step<false><<<grd, blk, 0, stream>>>(ws3,  rf, out3);   // s1
    diffeo_step<false><<<grd, blk, 0, stream>>>(out3, rf, ws3);    // s2
    diffeo_step<false><<<grd, blk, 0, stream>>>(ws3,  rf, out3);   // s3
    diffeo_step<false><<<grd, blk, 0, stream>>>(out3, rf, ws3);    // s4
    diffeo_step<false><<<grd, blk, 0, stream>>>(ws3,  rf, out3);   // s5
    diffeo_step<false><<<grd, blk, 0, stream>>>(out3, rf, ws3);    // s6
    // step 7: interleaved ws -> PLANAR d_out (full overwrite, no aliasing)
    diffeo_step<true ><<<grd, blk, 0, stream>>>(ws3,  rf, d_out);  // s7
}